// Round 10
// baseline (68.167 us; speedup 1.0000x reference)
//
#include <hip/hip_runtime.h>
#include <stdint.h>

#define BATCH 64
#define MDIM 512
#define KDIM 256
#define BM 128       // rows per block
#define BN 64        // cols per block
#define BK 32
#define NKSTEP 8     // KDIM / BK
#define TILES_M 4    // 512/128
#define TILES_N 8    // 512/64
#define NTILES 32    // per batch
#define NBLK 2048    // 64 * 32

typedef __attribute__((ext_vector_type(8))) short short8;
typedef __attribute__((ext_vector_type(4))) float f32x4;
typedef __attribute__((ext_vector_type(4))) unsigned int u32x4;

// HW packed f32->bf16 RNE (no builtin on gfx950; single instr)
__device__ __forceinline__ unsigned int cvt_pk(float lo, float hi) {
  unsigned int r;
  asm("v_cvt_pk_bf16_f32 %0, %1, %2" : "=v"(r) : "v"(lo), "v"(hi));
  return r;
}

// Raw barrier: waits LDS ops only; global loads stay in flight.
#define BARRIER()                                         \
  {                                                       \
    asm volatile("s_waitcnt lgkmcnt(0)" ::: "memory");    \
    __builtin_amdgcn_s_barrier();                         \
    asm volatile("" ::: "memory");                        \
  }

#define SQ4(s_, f) { s_ += (f).x*(f).x + (f).y*(f).y + (f).z*(f).z + (f).w*(f).w; }

__device__ __forceinline__ float waveRedSum(float v) {
  v += __shfl_xor(v, 32);
  v += __shfl_xor(v, 16);
  v += __shfl_xor(v, 8);
  v += __shfl_xor(v, 4);
  v += __shfl_xor(v, 2);
  v += __shfl_xor(v, 1);
  return v;
}

// 256 threads = 4 waves (2x2); block = 128x64 tile; wave tile 64x32.
// Small LDS (24.8KB) + low VGPR (launch_bounds(256,5) cap ~102) -> 5
// independent barrier groups per CU: stalls of one group overlap with
// compute of the others. Swizzle u^((row>>1)&3) over 64B rows: <=2-way
// bank aliasing on ds_read_b128 (free).
__global__ __launch_bounds__(256, 5) void pot_gemm_reduce(
    const float* __restrict__ V, const float* __restrict__ Ae,
    float* __restrict__ part) {
  const int bid = blockIdx.x;
  const int lin = (bid & 7) * 256 + (bid >> 3);   // XCD swizzle (2048%8==0)
  const int b   = lin >> 5;       // batch
  const int t   = lin & 31;       // tile
  const int tm  = t >> 3;         // 0..3  (128-row strip)
  const int tn  = t & 7;          // 0..7  (64-col strip)

  const int tid  = threadIdx.x;   // 0..255
  const int w    = tid >> 6;      // wave 0..3
  const int lane = tid & 63;
  const int wr   = w >> 1;        // 0..1 : 64-row strip
  const int wc   = w & 1;         // 0..1 : 32-col strip
  const int fr   = lane & 15;
  const int fk   = lane >> 4;

  // A staging: row = tid>>1, 16-float half = tid&1 (units 2h, 2h+1)
  const int arow  = tid >> 1;
  const int ahalf = tid & 1;
  // B staging: row = tid>>2, unit = tid&3
  const int brow  = tid >> 2;
  const int bunit = tid & 3;

  __shared__ short As[2][BM][BK];   // 16 KiB
  __shared__ short Bs[2][BN][BK];   // 8 KiB
  __shared__ float nvs[BM];
  __shared__ float nbs[BN];
  __shared__ float red[4][4];

  const float* Vg = V  + ((size_t)b * MDIM + tm * BM + arow) * KDIM + ahalf * 16;
  const float* Bg = Ae + ((size_t)b * MDIM + tn * BN + brow) * KDIM + bunit * 8;

  float sqa = 0.f, sqb = 0.f;
  f32x4 acc[4][2];
#pragma unroll
  for (int m = 0; m < 4; ++m)
#pragma unroll
    for (int n = 0; n < 2; ++n)
      acc[m][n] = (f32x4){0.f, 0.f, 0.f, 0.f};

  float4 ra0, ra1, ra2, ra3, rb0, rb1;   // 24 staging regs (1-deep)

#define ISSUE(k)                                                              \
  {                                                                           \
    const float4* pa = reinterpret_cast<const float4*>(Vg + (k) * BK);        \
    const float4* pb = reinterpret_cast<const float4*>(Bg + (k) * BK);        \
    ra0 = pa[0]; ra1 = pa[1]; ra2 = pa[2]; ra3 = pa[3];                       \
    rb0 = pb[0]; rb1 = pb[1];                                                 \
  }

#define WRITE(buf)                                                            \
  {                                                                           \
    u32x4 wa0, wa1, wb;                                                       \
    wa0[0] = cvt_pk(ra0.x, ra0.y); wa0[1] = cvt_pk(ra0.z, ra0.w);             \
    wa0[2] = cvt_pk(ra1.x, ra1.y); wa0[3] = cvt_pk(ra1.z, ra1.w);             \
    wa1[0] = cvt_pk(ra2.x, ra2.y); wa1[1] = cvt_pk(ra2.z, ra2.w);             \
    wa1[2] = cvt_pk(ra3.x, ra3.y); wa1[3] = cvt_pk(ra3.z, ra3.w);             \
    wb[0]  = cvt_pk(rb0.x, rb0.y); wb[1]  = cvt_pk(rb0.z, rb0.w);             \
    wb[2]  = cvt_pk(rb1.x, rb1.y); wb[3]  = cvt_pk(rb1.z, rb1.w);             \
    SQ4(sqa, ra0); SQ4(sqa, ra1); SQ4(sqa, ra2); SQ4(sqa, ra3);               \
    SQ4(sqb, rb0); SQ4(sqb, rb1);                                             \
    const int au0 = (ahalf * 2 + 0) ^ ((arow >> 1) & 3);                      \
    const int au1 = (ahalf * 2 + 1) ^ ((arow >> 1) & 3);                      \
    const int bu  = bunit ^ ((brow >> 1) & 3);                                \
    *reinterpret_cast<u32x4*>(&As[buf][arow][au0 * 8]) = wa0;                 \
    *reinterpret_cast<u32x4*>(&As[buf][arow][au1 * 8]) = wa1;                 \
    *reinterpret_cast<u32x4*>(&Bs[buf][brow][bu * 8])  = wb;                  \
  }

#define COMPUTE(buf)                                                          \
  {                                                                           \
    short8 af[4], bf[2];                                                      \
    const int ru = (fk ^ ((fr >> 1) & 3)) * 8;                                \
    _Pragma("unroll")                                                         \
    for (int m = 0; m < 4; ++m)                                               \
      af[m] = *reinterpret_cast<const short8*>(                               \
          &As[buf][wr * 64 + m * 16 + fr][ru]);                               \
    _Pragma("unroll")                                                         \
    for (int n = 0; n < 2; ++n)                                               \
      bf[n] = *reinterpret_cast<const short8*>(                               \
          &Bs[buf][wc * 32 + n * 16 + fr][ru]);                               \
    _Pragma("unroll")                                                         \
    for (int m = 0; m < 4; ++m)                                               \
      _Pragma("unroll")                                                       \
      for (int n = 0; n < 2; ++n)                                             \
        acc[m][n] = __builtin_amdgcn_mfma_f32_16x16x32_bf16(                  \
            af[m], bf[n], acc[m][n], 0, 0, 0);                                \
  }

  // prologue
  ISSUE(0);
  WRITE(0);
  BARRIER();

#pragma unroll
  for (int k = 0; k < NKSTEP; ++k) {
    if (k + 1 < NKSTEP) ISSUE(k + 1);        // loads in flight over COMPUTE
    COMPUTE(k & 1);
    if (k + 1 < NKSTEP) WRITE((k + 1) & 1);
    BARRIER();
  }

  // half-norms 0.5*||row||^2
  {
    float va = sqa + __shfl_xor(sqa, 1);          // A row split over tid&1
    if (ahalf == 0) nvs[arow] = 0.5f * va;
    float vb = sqb;                                // B row split over tid&3
    vb += __shfl_xor(vb, 1); vb += __shfl_xor(vb, 2);
    if (bunit == 0) nbs[brow] = 0.5f * vb;
  }
  BARRIER();

  // epilogue: C = hr + hc - dot; T = 2^(C*k2); 4 scalar reductions
  float hr[4][4], hc[2];
#pragma unroll
  for (int m = 0; m < 4; ++m)
#pragma unroll
    for (int r = 0; r < 4; ++r)
      hr[m][r] = nvs[wr * 64 + m * 16 + fk * 4 + r];
#pragma unroll
  for (int n = 0; n < 2; ++n)
    hc[n] = nbs[wc * 32 + n * 16 + fr];

  const bool rowmask = (tm == 0) && (wr == 0) && (fk == 0);
  const bool colmask = (tn == 0) && (wc == 0) && (fr == 0);
  const float k2 = -1.0e-3f * 1.4426950408889634f;  // -log2(e)/beta

  float s0p = 0.f, ctp = 0.f, rsp = 0.f, csp = 0.f;
#pragma unroll
  for (int m = 0; m < 4; ++m) {
#pragma unroll
    for (int n = 0; n < 2; ++n) {
#pragma unroll
      for (int r = 0; r < 4; ++r) {
        float Cv = hr[m][r] + hc[n] - acc[m][n][r];
        float T = exp2f(Cv * k2);
        s0p += T;
        ctp += Cv * T;
        if (m == 0 && r == 0) rsp += rowmask ? T : 0.f;  // global row 0
        if (n == 0)           csp += colmask ? T : 0.f;  // global col 0
      }
    }
  }

  s0p = waveRedSum(s0p);
  ctp = waveRedSum(ctp);
  rsp = waveRedSum(rsp);
  csp = waveRedSum(csp);
  if (lane == 0) { red[w][0] = s0p; red[w][1] = ctp; red[w][2] = rsp; red[w][3] = csp; }
  __syncthreads();
  if (tid == 0) {
    float s0 = 0.f, ct = 0.f, rs = 0.f, cs = 0.f;
#pragma unroll
    for (int i = 0; i < 4; ++i) {
      s0 += red[i][0]; ct += red[i][1]; rs += red[i][2]; cs += red[i][3];
    }
    float* p = part + ((size_t)(b * NTILES + t)) * 4;
    p[0] = s0; p[1] = ct; p[2] = rs; p[3] = cs;
  }
}

// One wave; thread b = batch b: deterministic tile reduce + 10-iter scalar
// recurrence + batch mean.
__global__ __launch_bounds__(64) void pot_finalize(
    const float* __restrict__ part, float* __restrict__ out) {
  const int b = threadIdx.x;
  float S0 = 0.f, CT = 0.f, RS = 0.f, CS = 0.f;
#pragma unroll
  for (int t = 0; t < NTILES; ++t) {
    const float* p = part + ((size_t)(b * NTILES + t)) * 4;
    S0 += p[0]; CT += p[1]; RS += p[2]; CS += p[3];
  }
  const float a0 = 1.0f / (float)MDIM;
  const float b0 = 1.0f / (float)MDIM;
  const float s  = (float)MDIM;
  float c = s / S0;
#pragma unroll
  for (int i = 0; i < 10; ++i) {
    float ka = fminf(a0 / (c * RS), 1.0f);
    float kb = fminf(b0 / (ka * c * CS), 1.0f);
    c = s * ka * kb / S0;
  }
  float D = c * CT;
  D = waveRedSum(D);
  if (b == 0) out[0] = D * (1.0f / (float)BATCH);
}

extern "C" void kernel_launch(void* const* d_in, const int* in_sizes, int n_in,
                              void* d_out, int out_size, void* d_ws, size_t ws_size,
                              hipStream_t stream) {
  const float* V  = (const float*)d_in[0];   // v_emb [64,512,256] f32
  const float* Ae = (const float*)d_in[1];   // a_emb [64,512,256] f32
  float* out  = (float*)d_out;
  float* part = (float*)d_ws;                // [64][32][4] f32 partials

  pot_gemm_reduce<<<dim3(NBLK), 256, 0, stream>>>(V, Ae, part);
  pot_finalize<<<1, 64, 0, stream>>>(part, out);
}

// Round 11
// 56.280 us; speedup vs baseline: 1.2112x; 1.2112x over previous
//
#include <hip/hip_runtime.h>
#include <stdint.h>

#define BATCH 64
#define MDIM 512
#define KDIM 256
#define ROWS 64      // A rows per block (strip)
#define HCOLS 256    // cols per block (half)
#define NBLK 1024    // 64 batches x 8 strips x 2 halves

typedef __attribute__((ext_vector_type(8))) short short8;
typedef __attribute__((ext_vector_type(4))) float f32x4;
typedef __attribute__((ext_vector_type(4))) unsigned int u32x4;

// HW packed f32->bf16 RNE (no builtin on gfx950; single instr)
__device__ __forceinline__ unsigned int cvt_pk(float lo, float hi) {
  unsigned int r;
  asm("v_cvt_pk_bf16_f32 %0, %1, %2" : "=v"(r) : "v"(lo), "v"(hi));
  return r;
}

// Raw barrier: waits LDS ops only; global loads stay in flight.
#define BARRIER()                                         \
  {                                                       \
    asm volatile("s_waitcnt lgkmcnt(0)" ::: "memory");    \
    __builtin_amdgcn_s_barrier();                         \
    asm volatile("" ::: "memory");                        \
  }

__device__ __forceinline__ float waveRedSum(float v) {
  v += __shfl_xor(v, 32);
  v += __shfl_xor(v, 16);
  v += __shfl_xor(v, 8);
  v += __shfl_xor(v, 4);
  v += __shfl_xor(v, 2);
  v += __shfl_xor(v, 1);
  return v;
}

// Block = (batch, 64-row A strip, 256-col half). 512 threads = 8 waves.
// A staged to LDS once with ROTATION layout p=(u+row)&31 (rows are 512B =
// bank-aligned, so reads at fixed fk span 16 consecutive units -> each
// bank-group exactly 2x = free). ONE barrier; K-loop reads B straight from
// global through a NAMED 2-deep register pipeline (st[2][4], fully unrolled,
// static indices) so loads stay in flight; no ds_writes, no barriers.
// launch_bounds(512,3): VGPR cap ~170 -> allocator has room (R9's collapse
// to 44 regs serialized everything; R8's (512,8) cap 64 spilled).
__global__ __launch_bounds__(512, 3) void pot_gemm_reduce(
    const float* __restrict__ V, const float* __restrict__ Ae,
    float* __restrict__ part) {
  const int bid = blockIdx.x;
  const int lin = (bid & 7) * 128 + (bid >> 3);  // XCD swizzle: 8 batches/XCD
  const int b     = lin >> 4;
  const int strip = (lin >> 1) & 7;
  const int half  = lin & 1;

  const int tid  = threadIdx.x;
  const int w    = tid >> 6;       // wave 0..7
  const int lane = tid & 63;
  const int fr   = lane & 15;      // fragment row/col within 16
  const int fk   = lane >> 4;      // k-window 0..3

  __shared__ short As[ROWS][KDIM];  // 32 KiB bf16, rotation p=(u+row)&31
  __shared__ float nvs[ROWS];

  // ---- stage A strip (64x256 fp32 -> bf16) + row half-norms ----
  {
    const int row = tid >> 3;
    const int j   = tid & 7;
    const float* Ar = V + ((size_t)b * MDIM + strip * ROWS + row) * KDIM;
    float sq = 0.f;
#pragma unroll
    for (int i = 0; i < 4; ++i) {
      const int u = j * 4 + i;
      const float4* p = reinterpret_cast<const float4*>(Ar + u * 8);
      float4 x = p[0], y = p[1];
      u32x4 wv;
      wv[0] = cvt_pk(x.x, x.y); wv[1] = cvt_pk(x.z, x.w);
      wv[2] = cvt_pk(y.x, y.y); wv[3] = cvt_pk(y.z, y.w);
      sq += x.x * x.x + x.y * x.y + x.z * x.z + x.w * x.w;
      sq += y.x * y.x + y.y * y.y + y.z * y.z + y.w * y.w;
      *reinterpret_cast<u32x4*>(&As[row][((u + row) & 31) * 8]) = wv;
    }
    sq += __shfl_xor(sq, 1);
    sq += __shfl_xor(sq, 2);
    sq += __shfl_xor(sq, 4);
    if (j == 0) nvs[row] = 0.5f * sq;
  }

  // ---- issue first B loads BEFORE the barrier (stay in flight) ----
  const int gcb = half * HCOLS + w * 32;   // wave's global col base
  const float* B0 = Ae + ((size_t)b * MDIM + gcb + fr) * KDIM + fk * 8;
  const float* B1 = B0 + 16 * KDIM;

  float4 st[2][4];   // named 2-deep pipeline: 32 VGPRs the allocator MUST keep
  st[0][0] = *reinterpret_cast<const float4*>(B0);
  st[0][1] = *reinterpret_cast<const float4*>(B0 + 4);
  st[0][2] = *reinterpret_cast<const float4*>(B1);
  st[0][3] = *reinterpret_cast<const float4*>(B1 + 4);

  BARRIER();   // lgkm-only: A visible; B loads still in flight

  f32x4 acc[4][2];
#pragma unroll
  for (int m = 0; m < 4; ++m)
#pragma unroll
    for (int n = 0; n < 2; ++n)
      acc[m][n] = (f32x4){0.f, 0.f, 0.f, 0.f};
  float sqb0 = 0.f, sqb1 = 0.f;

#pragma unroll
  for (int ks = 0; ks < 8; ++ks) {           // fully unrolled: static indices
    const int cur = ks & 1;
    const int nxt = cur ^ 1;
    if (ks < 7) {                            // issue ks+1 before consuming ks
      st[nxt][0] = *reinterpret_cast<const float4*>(B0 + (ks + 1) * 32);
      st[nxt][1] = *reinterpret_cast<const float4*>(B0 + (ks + 1) * 32 + 4);
      st[nxt][2] = *reinterpret_cast<const float4*>(B1 + (ks + 1) * 32);
      st[nxt][3] = *reinterpret_cast<const float4*>(B1 + (ks + 1) * 32 + 4);
    }
    // consume st[cur]
    u32x4 t0, t1;
    t0[0] = cvt_pk(st[cur][0].x, st[cur][0].y);
    t0[1] = cvt_pk(st[cur][0].z, st[cur][0].w);
    t0[2] = cvt_pk(st[cur][1].x, st[cur][1].y);
    t0[3] = cvt_pk(st[cur][1].z, st[cur][1].w);
    t1[0] = cvt_pk(st[cur][2].x, st[cur][2].y);
    t1[1] = cvt_pk(st[cur][2].z, st[cur][2].w);
    t1[2] = cvt_pk(st[cur][3].x, st[cur][3].y);
    t1[3] = cvt_pk(st[cur][3].z, st[cur][3].w);
    sqb0 += st[cur][0].x * st[cur][0].x + st[cur][0].y * st[cur][0].y +
            st[cur][0].z * st[cur][0].z + st[cur][0].w * st[cur][0].w;
    sqb0 += st[cur][1].x * st[cur][1].x + st[cur][1].y * st[cur][1].y +
            st[cur][1].z * st[cur][1].z + st[cur][1].w * st[cur][1].w;
    sqb1 += st[cur][2].x * st[cur][2].x + st[cur][2].y * st[cur][2].y +
            st[cur][2].z * st[cur][2].z + st[cur][2].w * st[cur][2].w;
    sqb1 += st[cur][3].x * st[cur][3].x + st[cur][3].y * st[cur][3].y +
            st[cur][3].z * st[cur][3].z + st[cur][3].w * st[cur][3].w;
    short8 bf0 = *reinterpret_cast<short8*>(&t0);
    short8 bf1 = *reinterpret_cast<short8*>(&t1);

    // A fragments: unit = (4ks + fk + row) & 31 (rotation; conflict-free)
    short8 af0 = *reinterpret_cast<const short8*>(
        &As[fr][((4 * ks + fk + fr) & 31) * 8]);
    short8 af1 = *reinterpret_cast<const short8*>(
        &As[16 + fr][((4 * ks + fk + 16 + fr) & 31) * 8]);
    short8 af2 = *reinterpret_cast<const short8*>(
        &As[32 + fr][((4 * ks + fk + fr) & 31) * 8]);
    short8 af3 = *reinterpret_cast<const short8*>(
        &As[48 + fr][((4 * ks + fk + 16 + fr) & 31) * 8]);

    acc[0][0] = __builtin_amdgcn_mfma_f32_16x16x32_bf16(af0, bf0, acc[0][0], 0, 0, 0);
    acc[0][1] = __builtin_amdgcn_mfma_f32_16x16x32_bf16(af0, bf1, acc[0][1], 0, 0, 0);
    acc[1][0] = __builtin_amdgcn_mfma_f32_16x16x32_bf16(af1, bf0, acc[1][0], 0, 0, 0);
    acc[1][1] = __builtin_amdgcn_mfma_f32_16x16x32_bf16(af1, bf1, acc[1][1], 0, 0, 0);
    acc[2][0] = __builtin_amdgcn_mfma_f32_16x16x32_bf16(af2, bf0, acc[2][0], 0, 0, 0);
    acc[2][1] = __builtin_amdgcn_mfma_f32_16x16x32_bf16(af2, bf1, acc[2][1], 0, 0, 0);
    acc[3][0] = __builtin_amdgcn_mfma_f32_16x16x32_bf16(af3, bf0, acc[3][0], 0, 0, 0);
    acc[3][1] = __builtin_amdgcn_mfma_f32_16x16x32_bf16(af3, bf1, acc[3][1], 0, 0, 0);
  }

  // ---- epilogue ----
  sqb0 += __shfl_xor(sqb0, 16); sqb0 += __shfl_xor(sqb0, 32);
  sqb1 += __shfl_xor(sqb1, 16); sqb1 += __shfl_xor(sqb1, 32);
  const float hc0 = 0.5f * sqb0;
  const float hc1 = 0.5f * sqb1;

  float hr[4][4];
#pragma unroll
  for (int m = 0; m < 4; ++m)
#pragma unroll
    for (int r = 0; r < 4; ++r)
      hr[m][r] = nvs[m * 16 + fk * 4 + r];

  const bool rowmask = (strip == 0) && (fk == 0);            // global row 0
  const bool colmask = (half == 0) && (w == 0) && (fr == 0); // global col 0
  const float k2 = -1.0e-3f * 1.4426950408889634f;           // -log2(e)/beta

  float s0p = 0.f, ctp = 0.f, rsp = 0.f, csp = 0.f;
#pragma unroll
  for (int m = 0; m < 4; ++m) {
#pragma unroll
    for (int n = 0; n < 2; ++n) {
#pragma unroll
      for (int r = 0; r < 4; ++r) {
        float Cv = hr[m][r] + (n ? hc1 : hc0) - acc[m][n][r];
        float T = exp2f(Cv * k2);
        s0p += T;
        ctp += Cv * T;
        if (m == 0 && r == 0) rsp += rowmask ? T : 0.f;
        if (n == 0)           csp += colmask ? T : 0.f;
      }
    }
  }

  s0p = waveRedSum(s0p);
  ctp = waveRedSum(ctp);
  rsp = waveRedSum(rsp);
  csp = waveRedSum(csp);
  if (lane == 0) {
    float* p = part + (((size_t)((b * 16 + strip * 2 + half)) * 8 + w)) * 4;
    p[0] = s0p; p[1] = ctp; p[2] = rsp; p[3] = csp;
  }
}

// 256 threads: 4 threads per batch, each sums 32 of the 128 wave-partials,
// shfl-combine, per-batch recurrence, LDS tree for the batch mean.
__global__ __launch_bounds__(256) void pot_finalize(
    const float* __restrict__ part, float* __restrict__ out) {
  __shared__ float dred[BATCH];
  const int t = threadIdx.x;
  const int batch = t >> 2;
  const int q = t & 3;

  float S0 = 0.f, CT = 0.f, RS = 0.f, CS = 0.f;
  const f32x4* p4 = reinterpret_cast<const f32x4*>(part);
#pragma unroll
  for (int i = 0; i < 32; ++i) {
    f32x4 v = p4[batch * 128 + q * 32 + i];
    S0 += v[0]; CT += v[1]; RS += v[2]; CS += v[3];
  }
  S0 += __shfl_xor(S0, 1); S0 += __shfl_xor(S0, 2);
  CT += __shfl_xor(CT, 1); CT += __shfl_xor(CT, 2);
  RS += __shfl_xor(RS, 1); RS += __shfl_xor(RS, 2);
  CS += __shfl_xor(CS, 1); CS += __shfl_xor(CS, 2);

  if (q == 0) {
    const float a0 = 1.0f / (float)MDIM;
    const float b0 = 1.0f / (float)MDIM;
    const float s  = (float)MDIM;
    float c = s / S0;
#pragma unroll
    for (int i = 0; i < 10; ++i) {
      float ka = fminf(a0 / (c * RS), 1.0f);
      float kb = fminf(b0 / (ka * c * CS), 1.0f);
      c = s * ka * kb / S0;
    }
    dred[batch] = c * CT;
  }
  __syncthreads();
  if (t < 64) {
    float D = waveRedSum(dred[t]);
    if (t == 0) out[0] = D * (1.0f / (float)BATCH);
  }
}

extern "C" void kernel_launch(void* const* d_in, const int* in_sizes, int n_in,
                              void* d_out, int out_size, void* d_ws, size_t ws_size,
                              hipStream_t stream) {
  const float* V  = (const float*)d_in[0];   // v_emb [64,512,256] f32
  const float* Ae = (const float*)d_in[1];   // a_emb [64,512,256] f32
  float* out  = (float*)d_out;
  float* part = (float*)d_ws;                // [1024][8][4] f32 = 128 KiB

  pot_gemm_reduce<<<dim3(NBLK), 512, 0, stream>>>(V, Ae, part);
  pot_finalize<<<1, 256, 0, stream>>>(part, out);
}

// Round 12
// 35.730 us; speedup vs baseline: 1.9078x; 1.5751x over previous
//
#include <hip/hip_runtime.h>
#include <stdint.h>

#define BATCH 64
#define MDIM 512
#define KDIM 256
#define BM 128
#define BN 128
#define BK 64        // doubled K-step: 4 main barriers instead of 8
#define NKSTEP 4     // KDIM / BK
#define NTILES 16    // (512/128)^2
#define NBLK 1024

typedef __attribute__((ext_vector_type(8))) short short8;
typedef __attribute__((ext_vector_type(4))) float f32x4;
typedef __attribute__((ext_vector_type(4))) unsigned int u32x4;

// HW packed f32->bf16 RNE (no builtin on gfx950; single instr)
__device__ __forceinline__ unsigned int cvt_pk(float lo, float hi) {
  unsigned int r;
  asm("v_cvt_pk_bf16_f32 %0, %1, %2" : "=v"(r) : "v"(lo), "v"(hi));
  return r;
}

// Raw barrier: waits LDS ops only; global loads stay in flight.
#define BARRIER()                                         \
  {                                                       \
    asm volatile("s_waitcnt lgkmcnt(0)" ::: "memory");    \
    __builtin_amdgcn_s_barrier();                         \
    asm volatile("" ::: "memory");                        \
  }

#define SQ4(s_, f) { s_ += (f).x*(f).x + (f).y*(f).y + (f).z*(f).z + (f).w*(f).w; }

__device__ __forceinline__ float waveRedSum(float v) {
  v += __shfl_xor(v, 32);
  v += __shfl_xor(v, 16);
  v += __shfl_xor(v, 8);
  v += __shfl_xor(v, 4);
  v += __shfl_xor(v, 2);
  v += __shfl_xor(v, 1);
  return v;
}

// 512 threads = 8 waves (2x4); block = 128x128 tile; wave tile 64x32.
// BK=64: rows are 128B = 8 16B-units; swizzle u^(row&7) is conflict-free
// for both the staged writes and the frag reads (8-lane phases cover all
// 8 bank-groups). 1-deep named prefetch (32 regs) = R6's latency budget.
__global__ __launch_bounds__(512, 4) void pot_gemm_reduce(
    const float* __restrict__ V, const float* __restrict__ Ae,
    float* __restrict__ part) {
  const int bid = blockIdx.x;
  const int lin = (bid & 7) * 128 + (bid >> 3);   // XCD swizzle (1024%8==0)
  const int b   = lin >> 4;
  const int t   = lin & 15;
  const int tm  = t >> 2;
  const int tn  = t & 3;

  const int tid  = threadIdx.x;
  const int w    = tid >> 6;
  const int lane = tid & 63;
  const int wr   = w >> 2;         // 0..1 : 64-row strip
  const int wc   = w & 3;          // 0..3 : 32-col strip
  const int srow = tid >> 2;       // staging row 0..127
  const int sseg = tid & 3;        // staging 16-float segment (2 16B units)
  const int fr   = lane & 15;
  const int fk   = lane >> 4;

  __shared__ short As[2][BM][BK];   // 32 KiB
  __shared__ short Bs[2][BN][BK];   // 32 KiB
  __shared__ float nvs[BM];
  __shared__ float nbs[BN];
  __shared__ float red[8][4];

  const float* Vg = V  + ((size_t)b * MDIM + tm * BM + srow) * KDIM + sseg * 16;
  const float* Bg = Ae + ((size_t)b * MDIM + tn * BN + srow) * KDIM + sseg * 16;

  float sqa = 0.f, sqb = 0.f;
  f32x4 acc[4][2];
#pragma unroll
  for (int m = 0; m < 4; ++m)
#pragma unroll
    for (int n = 0; n < 2; ++n)
      acc[m][n] = (f32x4){0.f, 0.f, 0.f, 0.f};

  float4 ra0, ra1, ra2, ra3, rb0, rb1, rb2, rb3;   // 32 named staging regs

#define ISSUE(k)                                                              \
  {                                                                           \
    const float4* pa = reinterpret_cast<const float4*>(Vg + (k) * BK);        \
    const float4* pb = reinterpret_cast<const float4*>(Bg + (k) * BK);        \
    ra0 = pa[0]; ra1 = pa[1]; ra2 = pa[2]; ra3 = pa[3];                       \
    rb0 = pb[0]; rb1 = pb[1]; rb2 = pb[2]; rb3 = pb[3];                       \
  }

#define WRITE(buf)                                                            \
  {                                                                           \
    u32x4 wa0, wa1, wb0, wb1;                                                 \
    wa0[0] = cvt_pk(ra0.x, ra0.y); wa0[1] = cvt_pk(ra0.z, ra0.w);             \
    wa0[2] = cvt_pk(ra1.x, ra1.y); wa0[3] = cvt_pk(ra1.z, ra1.w);             \
    wa1[0] = cvt_pk(ra2.x, ra2.y); wa1[1] = cvt_pk(ra2.z, ra2.w);             \
    wa1[2] = cvt_pk(ra3.x, ra3.y); wa1[3] = cvt_pk(ra3.z, ra3.w);             \
    wb0[0] = cvt_pk(rb0.x, rb0.y); wb0[1] = cvt_pk(rb0.z, rb0.w);             \
    wb0[2] = cvt_pk(rb1.x, rb1.y); wb0[3] = cvt_pk(rb1.z, rb1.w);             \
    wb1[0] = cvt_pk(rb2.x, rb2.y); wb1[1] = cvt_pk(rb2.z, rb2.w);             \
    wb1[2] = cvt_pk(rb3.x, rb3.y); wb1[3] = cvt_pk(rb3.z, rb3.w);             \
    SQ4(sqa, ra0); SQ4(sqa, ra1); SQ4(sqa, ra2); SQ4(sqa, ra3);               \
    SQ4(sqb, rb0); SQ4(sqb, rb1); SQ4(sqb, rb2); SQ4(sqb, rb3);               \
    const int u0 = (2 * sseg + 0) ^ (srow & 7);                               \
    const int u1 = (2 * sseg + 1) ^ (srow & 7);                               \
    *reinterpret_cast<u32x4*>(&As[buf][srow][u0 * 8]) = wa0;                  \
    *reinterpret_cast<u32x4*>(&As[buf][srow][u1 * 8]) = wa1;                  \
    *reinterpret_cast<u32x4*>(&Bs[buf][srow][u0 * 8]) = wb0;                  \
    *reinterpret_cast<u32x4*>(&Bs[buf][srow][u1 * 8]) = wb1;                  \
  }

#define COMPUTE(buf)                                                          \
  {                                                                           \
    _Pragma("unroll")                                                         \
    for (int kk = 0; kk < 2; ++kk) {                                          \
      short8 af[4], bf[2];                                                    \
      _Pragma("unroll")                                                       \
      for (int m = 0; m < 4; ++m) {                                           \
        const int row = wr * 64 + m * 16 + fr;                                \
        af[m] = *reinterpret_cast<const short8*>(                             \
            &As[buf][row][((4 * kk + fk) ^ (row & 7)) * 8]);                  \
      }                                                                       \
      _Pragma("unroll")                                                       \
      for (int n = 0; n < 2; ++n) {                                           \
        const int row = wc * 32 + n * 16 + fr;                                \
        bf[n] = *reinterpret_cast<const short8*>(                             \
            &Bs[buf][row][((4 * kk + fk) ^ (row & 7)) * 8]);                  \
      }                                                                       \
      _Pragma("unroll")                                                       \
      for (int m = 0; m < 4; ++m)                                             \
        _Pragma("unroll")                                                     \
        for (int n = 0; n < 2; ++n)                                           \
          acc[m][n] = __builtin_amdgcn_mfma_f32_16x16x32_bf16(                \
              af[m], bf[n], acc[m][n], 0, 0, 0);                              \
    }                                                                         \
  }

  // prologue
  ISSUE(0);
  WRITE(0);
  BARRIER();

#pragma unroll
  for (int k = 0; k < NKSTEP; ++k) {
    if (k + 1 < NKSTEP) ISSUE(k + 1);        // loads in flight over COMPUTE
    COMPUTE(k & 1);
    if (k + 1 < NKSTEP) WRITE((k + 1) & 1);
    BARRIER();
  }

  // half-norms 0.5*||row||^2 (each thread covered cols sseg*16 + k*64)
  {
    float va = sqa;
    va += __shfl_xor(va, 1); va += __shfl_xor(va, 2);
    float vb = sqb;
    vb += __shfl_xor(vb, 1); vb += __shfl_xor(vb, 2);
    if (sseg == 0) { nvs[srow] = 0.5f * va; nbs[srow] = 0.5f * vb; }
  }
  BARRIER();

  // epilogue: hoisted norms; C = hr + hc - dot; T = 2^(C*k2)
  float hr[4][4], hc[2];
#pragma unroll
  for (int m = 0; m < 4; ++m)
#pragma unroll
    for (int r = 0; r < 4; ++r)
      hr[m][r] = nvs[wr * 64 + m * 16 + fk * 4 + r];
#pragma unroll
  for (int n = 0; n < 2; ++n)
    hc[n] = nbs[wc * 32 + n * 16 + fr];

  const bool rowmask = (tm == 0) && (wr == 0) && (fk == 0);
  const bool colmask = (tn == 0) && (wc == 0) && (fr == 0);
  const float k2 = -1.0e-3f * 1.4426950408889634f;  // -log2(e)/beta

  float s0p = 0.f, ctp = 0.f, rsp = 0.f, csp = 0.f;
#pragma unroll
  for (int m = 0; m < 4; ++m) {
#pragma unroll
    for (int n = 0; n < 2; ++n) {
#pragma unroll
      for (int r = 0; r < 4; ++r) {
        float Cv = hr[m][r] + hc[n] - acc[m][n][r];
        float T = exp2f(Cv * k2);
        s0p += T;
        ctp += Cv * T;
        if (m == 0 && r == 0) rsp += rowmask ? T : 0.f;  // global row 0
        if (n == 0)           csp += colmask ? T : 0.f;  // global col 0
      }
    }
  }

  s0p = waveRedSum(s0p);
  ctp = waveRedSum(ctp);
  rsp = waveRedSum(rsp);
  csp = waveRedSum(csp);
  if (lane == 0) { red[w][0] = s0p; red[w][1] = ctp; red[w][2] = rsp; red[w][3] = csp; }
  BARRIER();
  if (tid == 0) {
    float s0 = 0.f, ct = 0.f, rs = 0.f, cs = 0.f;
#pragma unroll
    for (int i = 0; i < 8; ++i) {
      s0 += red[i][0]; ct += red[i][1]; rs += red[i][2]; cs += red[i][3];
    }
    float* p = part + ((size_t)(b * NTILES + t)) * 4;
    p[0] = s0; p[1] = ct; p[2] = rs; p[3] = cs;
  }
}

// One wave; thread b = batch b: deterministic tile reduce + 10-iter scalar
// recurrence + batch mean.
__global__ __launch_bounds__(64) void pot_finalize(
    const float* __restrict__ part, float* __restrict__ out) {
  const int b = threadIdx.x;
  float S0 = 0.f, CT = 0.f, RS = 0.f, CS = 0.f;
#pragma unroll
  for (int t = 0; t < NTILES; ++t) {
    const float* p = part + ((size_t)(b * NTILES + t)) * 4;
    S0 += p[0]; CT += p[1]; RS += p[2]; CS += p[3];
  }
  const float a0 = 1.0f / (float)MDIM;
  const float b0 = 1.0f / (float)MDIM;
  const float s  = (float)MDIM;
  float c = s / S0;
#pragma unroll
  for (int i = 0; i < 10; ++i) {
    float ka = fminf(a0 / (c * RS), 1.0f);
    float kb = fminf(b0 / (ka * c * CS), 1.0f);
    c = s * ka * kb / S0;
  }
  float D = c * CT;
  D = waveRedSum(D);
  if (b == 0) out[0] = D * (1.0f / (float)BATCH);
}

extern "C" void kernel_launch(void* const* d_in, const int* in_sizes, int n_in,
                              void* d_out, int out_size, void* d_ws, size_t ws_size,
                              hipStream_t stream) {
  const float* V  = (const float*)d_in[0];   // v_emb [64,512,256] f32
  const float* Ae = (const float*)d_in[1];   // a_emb [64,512,256] f32
  float* out  = (float*)d_out;
  float* part = (float*)d_ws;                // [64][16][4] f32 partials

  pot_gemm_reduce<<<dim3(NBLK), 512, 0, stream>>>(V, Ae, part);
  pot_finalize<<<1, 64, 0, stream>>>(part, out);
}